// Round 4
// baseline (354.648 us; speedup 1.0000x reference)
//
#include <hip/hip_runtime.h>
#include <hip/hip_bf16.h>

#define B_ 4
#define T_ 512
#define H_ 1024
#define D_ 32
#define NH_ 32
#define E_ 256
#define S_ 768
#define SCALING_ 0.17677669529663687f

typedef __bf16 bf16x8 __attribute__((ext_vector_type(8)));
typedef __bf16 bf16x4 __attribute__((ext_vector_type(4)));
typedef float f32x16 __attribute__((ext_vector_type(16)));
typedef unsigned int u32x4 __attribute__((ext_vector_type(4)));

// ---------------------------------------------------------------------------
// Kernel 1: PBC KV expansion (blocks 0..1535) + out_w fp32->bf16 conversion
// (blocks 1536..2559) fused into one launch.
// ---------------------------------------------------------------------------
__global__ __launch_bounds__(256) void prep_kernel(
    const float* __restrict__ k, const float* __restrict__ v,
    const int* __restrict__ outcell, __bf16* __restrict__ Kx,
    __bf16* __restrict__ Vt, const float* __restrict__ w,
    __bf16* __restrict__ wbf) {
  __shared__ __bf16 vts[32][66];
  int tid = threadIdx.x;
  if (blockIdx.x >= 1536) {
    int idx = (blockIdx.x - 1536) * 1024 + tid * 4;
    float4 x = *(const float4*)(w + idx);
    bf16x4 o = {(__bf16)x.x, (__bf16)x.y, (__bf16)x.z, (__bf16)x.w};
    *(bf16x4*)(wbf + idx) = o;
    return;
  }
  int st = blockIdx.x % 12;
  int h = (blockIdx.x / 12) % NH_;
  int b = blockIdx.x / (12 * NH_);
  int s0 = st * 64;
  int s_l = tid >> 2;
  int dbase = (tid & 3) * 8;
  int s = s0 + s_l;
  int src = (s < T_) ? s : outcell[b * E_ + (s - T_)];
  const float* kp = k + ((size_t)(b * T_ + src)) * H_ + h * D_ + dbase;
  const float* vp = v + ((size_t)(b * T_ + src)) * H_ + h * D_ + dbase;
  float4 k0 = *(const float4*)kp;
  float4 k1 = *(const float4*)(kp + 4);
  float4 v0 = *(const float4*)vp;
  float4 v1 = *(const float4*)(vp + 4);
  bf16x8 kb;
  kb[0] = (__bf16)k0.x; kb[1] = (__bf16)k0.y; kb[2] = (__bf16)k0.z; kb[3] = (__bf16)k0.w;
  kb[4] = (__bf16)k1.x; kb[5] = (__bf16)k1.y; kb[6] = (__bf16)k1.z; kb[7] = (__bf16)k1.w;
  *(bf16x8*)(Kx + ((size_t)((b * NH_ + h) * S_ + s)) * D_ + dbase) = kb;
  vts[dbase + 0][s_l] = (__bf16)v0.x;
  vts[dbase + 1][s_l] = (__bf16)v0.y;
  vts[dbase + 2][s_l] = (__bf16)v0.z;
  vts[dbase + 3][s_l] = (__bf16)v0.w;
  vts[dbase + 4][s_l] = (__bf16)v1.x;
  vts[dbase + 5][s_l] = (__bf16)v1.y;
  vts[dbase + 6][s_l] = (__bf16)v1.z;
  vts[dbase + 7][s_l] = (__bf16)v1.w;
  __syncthreads();
  int d = tid >> 3, soff = (tid & 7) * 8;
  bf16x8 vv;
#pragma unroll
  for (int j = 0; j < 8; j++) vv[j] = vts[d][soff + j];
  *(bf16x8*)(Vt + ((size_t)((b * NH_ + h) * D_ + d)) * S_ + s0 + soff) = vv;
}

// ---------------------------------------------------------------------------
// Kernel 2: fused attention, transposed-score formulation.
// St = K.Q^T (A=K, B=Q^T) -> lane holds one t-column, 16 s-values.
// P stays in registers; PV B-fragment (P^T) built via __shfl_xor(32).
// O^T = Vt.P^T. Per-wave BL staging LDS [s][t] pitch 33 (conflict-free).
// One barrier total. LDS 17.4 KB.
// ---------------------------------------------------------------------------
#define BLPITCH 33   // u32 words per s-row
#define WWORDS 1056  // 32 * 33 words per wave region

__device__ __forceinline__ unsigned int pk2(float bv, float lv) {
  unsigned short ub = __builtin_bit_cast(unsigned short, (_Float16)bv);
  unsigned short ul = __builtin_bit_cast(unsigned short, (_Float16)lv);
  return (unsigned int)ub | ((unsigned int)ul << 16);
}

__device__ __forceinline__ float clampl(float l) {
  return (l <= 1e-5f) ? 0.f : fmaxf(l, 6.2e-5f);
}

__global__ __launch_bounds__(256, 4) void attn_kernel(
    const float* __restrict__ q, const __bf16* __restrict__ Kx,
    const __bf16* __restrict__ Vt, const float* __restrict__ bias,
    const float* __restrict__ law, float* __restrict__ attnws) {
  // [0, 16896): 4 x per-wave BL regions (aliased by opart in epilogue)
  // [16896, 17408): rspart[4][32]
  __shared__ __attribute__((aligned(16))) char smem[17408];
  unsigned int* BLw = (unsigned int*)(smem + (threadIdx.x >> 6) * (WWORDS * 4));
  float* opart = (float*)smem;  // [wave][d*33 + t]
  float* rspart = (float*)(smem + 16896);

  int tid = threadIdx.x;
  int tile = blockIdx.x & 15;
  int h = (blockIdx.x >> 4) & 31;
  int b = blockIdx.x >> 9;
  int t0 = tile * 32;
  int wave = tid >> 6, lane = tid & 63;
  int l31 = lane & 31, dh = lane >> 5;
  int srow = lane >> 3, sc4 = lane & 7;  // staging: row t=it*8+srow, s-col4 sc4

  // Q B-fragments (scaled, bf16): B[k=d=dh*8+j][n=t=l31]
  const float* qp = q + ((size_t)(b * T_ + t0 + l31)) * H_ + h * D_ + dh * 8;
  bf16x8 aq0, aq1;
#pragma unroll
  for (int j = 0; j < 8; j++) {
    aq0[j] = (__bf16)(qp[j] * SCALING_);
    aq1[j] = (__bf16)(qp[16 + j] * SCALING_);
  }

  int swbase = wave * 192;
  const float* bt = bias + ((size_t)(b * NH_ + h) * T_ + t0) * S_;
  const float* lt = law + ((size_t)(b * T_ + t0)) * S_;
  const __bf16* kxbase = Kx + (size_t)(b * NH_ + h) * S_ * D_;
  const __bf16* vbase = Vt + ((size_t)((b * NH_ + h) * D_ + l31)) * S_;

  float rs = 0.f;
  f32x16 oacc;
#pragma unroll
  for (int i = 0; i < 16; i++) oacc[i] = 0.f;

  // Prologue: stage chunk 0 into BL [s][t] layout
  {
    int cb = swbase;
#pragma unroll
    for (int it = 0; it < 4; ++it) {
      size_t ro = (size_t)(it * 8 + srow) * S_;
      float4 fb = *(const float4*)(bt + ro + cb + sc4 * 4);
      float4 fl = *(const float4*)(lt + ro + cb + sc4 * 4);
      int tl = it * 8 + srow;
      BLw[(sc4 * 4 + 0) * BLPITCH + tl] = pk2(fb.x, clampl(fl.x));
      BLw[(sc4 * 4 + 1) * BLPITCH + tl] = pk2(fb.y, clampl(fl.y));
      BLw[(sc4 * 4 + 2) * BLPITCH + tl] = pk2(fb.z, clampl(fl.z));
      BLw[(sc4 * 4 + 3) * BLPITCH + tl] = pk2(fb.w, clampl(fl.w));
    }
  }

#pragma unroll 1
  for (int c = 0; c < 6; ++c) {
    int cb = swbase + c * 32;
    // K A-fragments: A[m=s=cb+l31][k=d=dh*8+j]
    const __bf16* kp = kxbase + (size_t)(cb + l31) * D_ + dh * 8;
    bf16x8 kc0 = *(const bf16x8*)kp;
    bf16x8 kc1 = *(const bf16x8*)(kp + 16);
    // Vt A-fragments for PV: A[m=d=l31][k=s=cb+kk+dh*8+j]
    bf16x8 vc0 = *(const bf16x8*)(vbase + cb + dh * 8);
    bf16x8 vc1 = *(const bf16x8*)(vbase + cb + 16 + dh * 8);
    // prefetch next chunk's bias/law (the HBM-cold stream)
    float4 fbn[4], fln[4];
    if (c < 5) {
      int cn = cb + 32;
#pragma unroll
      for (int it = 0; it < 4; ++it) {
        size_t ro = (size_t)(it * 8 + srow) * S_;
        fbn[it] = *(const float4*)(bt + ro + cn + sc4 * 4);
        fln[it] = *(const float4*)(lt + ro + cn + sc4 * 4);
      }
    }
    // scores transposed: St[row=s][col=t]
    f32x16 sc;
#pragma unroll
    for (int i = 0; i < 16; i++) sc[i] = 0.f;
    sc = __builtin_amdgcn_mfma_f32_32x32x16_bf16(kc0, aq0, sc, 0, 0, 0);
    sc = __builtin_amdgcn_mfma_f32_32x32x16_bf16(kc1, aq1, sc, 0, 0, 0);
    // bias+law from LDS, exp, pack P pairs (s ascending within lane)
    unsigned int pp[8];
#pragma unroll
    for (int i = 0; i < 16; i += 2) {
      int sl = (i & 3) + 4 * dh + 8 * (i >> 2);
      unsigned int w0 = BLw[sl * BLPITCH + l31];
      unsigned int w1 = BLw[(sl + 1) * BLPITCH + l31];
      float bv0 = (float)__builtin_bit_cast(_Float16, (unsigned short)(w0 & 0xFFFFu));
      float lv0 = (float)__builtin_bit_cast(_Float16, (unsigned short)(w0 >> 16));
      float bv1 = (float)__builtin_bit_cast(_Float16, (unsigned short)(w1 & 0xFFFFu));
      float lv1 = (float)__builtin_bit_cast(_Float16, (unsigned short)(w1 >> 16));
      float e0 = (lv0 > 0.f) ? __expf(sc[i] + bv0) : 0.f;
      float e1 = (lv1 > 0.f) ? __expf(sc[i + 1] + bv1) : 0.f;
      rs += e0 + e1;
      unsigned short p0 = __builtin_bit_cast(unsigned short, (__bf16)(e0 * lv0));
      unsigned short p1 = __builtin_bit_cast(unsigned short, (__bf16)(e1 * lv1));
      pp[i >> 1] = (unsigned int)p0 | ((unsigned int)p1 << 16);
    }
    // build P^T B-fragments via xor-32 lane exchange
    unsigned int s10 = dh ? pp[0] : pp[2];
    unsigned int s11 = dh ? pp[1] : pp[3];
    unsigned int r10 = __shfl_xor(s10, 32);
    unsigned int r11 = __shfl_xor(s11, 32);
    unsigned int s20 = dh ? pp[4] : pp[6];
    unsigned int s21 = dh ? pp[5] : pp[7];
    unsigned int r20 = __shfl_xor(s20, 32);
    unsigned int r21 = __shfl_xor(s21, 32);
    union { unsigned int u[4]; bf16x8 v; } pf1, pf2;
    pf1.u[0] = dh ? r10 : pp[0];
    pf1.u[1] = dh ? r11 : pp[1];
    pf1.u[2] = dh ? pp[2] : r10;
    pf1.u[3] = dh ? pp[3] : r11;
    pf2.u[0] = dh ? r20 : pp[4];
    pf2.u[1] = dh ? r21 : pp[5];
    pf2.u[2] = dh ? pp[6] : r20;
    pf2.u[3] = dh ? pp[7] : r21;
    // O^T += Vt . P^T
    oacc = __builtin_amdgcn_mfma_f32_32x32x16_bf16(vc0, pf1.v, oacc, 0, 0, 0);
    oacc = __builtin_amdgcn_mfma_f32_32x32x16_bf16(vc1, pf2.v, oacc, 0, 0, 0);
    // stage next chunk (wave-local; DS in-order vs reads above)
    if (c < 5) {
#pragma unroll
      for (int it = 0; it < 4; ++it) {
        int tl = it * 8 + srow;
        BLw[(sc4 * 4 + 0) * BLPITCH + tl] = pk2(fbn[it].x, clampl(fln[it].x));
        BLw[(sc4 * 4 + 1) * BLPITCH + tl] = pk2(fbn[it].y, clampl(fln[it].y));
        BLw[(sc4 * 4 + 2) * BLPITCH + tl] = pk2(fbn[it].z, clampl(fln[it].z));
        BLw[(sc4 * 4 + 3) * BLPITCH + tl] = pk2(fbn[it].w, clampl(fln[it].w));
      }
    }
  }

  // ---- epilogue (one barrier) ----
  rs += __shfl_xor(rs, 32);
  if (lane < 32) rspart[wave * 32 + lane] = rs;
  // O^T partials: opart[wave][d*33 + t]  (own wave region, aliases own BL)
#pragma unroll
  for (int i = 0; i < 16; i++) {
    int d = (i & 3) + 4 * dh + 8 * (i >> 2);
    opart[wave * WWORDS + d * BLPITCH + l31] = oacc[i];
  }
  __syncthreads();

  int row = tid >> 3, c4 = (tid & 7) * 4;  // row=t, c4=d base
  float inv = 1.0f / (rspart[row] + rspart[32 + row] + rspart[64 + row] +
                      rspart[96 + row]);
  float acc[4] = {0.f, 0.f, 0.f, 0.f};
#pragma unroll
  for (int w = 0; w < 4; w++) {
#pragma unroll
    for (int e = 0; e < 4; e++)
      acc[e] += opart[w * WWORDS + (c4 + e) * BLPITCH + row];
  }
  float4 o;
  o.x = acc[0] * inv; o.y = acc[1] * inv; o.z = acc[2] * inv; o.w = acc[3] * inv;
  *(float4*)(attnws + (size_t)(b * T_ + t0 + row) * H_ + h * D_ + c4) = o;
}

// ---------------------------------------------------------------------------
// Kernel 3: LayerNorm over H=1024 per (b,t) row, output bf16
// ---------------------------------------------------------------------------
__global__ __launch_bounds__(256) void ln_kernel(const float* __restrict__ attn,
                                                 const float* __restrict__ lnw,
                                                 const float* __restrict__ lnb,
                                                 __bf16* __restrict__ lnbf) {
  int r = blockIdx.x;
  int tid = threadIdx.x;
  float4 x = ((const float4*)(attn + (size_t)r * H_))[tid];
  float s = x.x + x.y + x.z + x.w;
  float sq = x.x * x.x + x.y * x.y + x.z * x.z + x.w * x.w;
#pragma unroll
  for (int m = 1; m < 64; m <<= 1) {
    s += __shfl_xor(s, m);
    sq += __shfl_xor(sq, m);
  }
  __shared__ float ss[4], ssq[4];
  if ((tid & 63) == 0) { ss[tid >> 6] = s; ssq[tid >> 6] = sq; }
  __syncthreads();
  s = ss[0] + ss[1] + ss[2] + ss[3];
  sq = ssq[0] + ssq[1] + ssq[2] + ssq[3];
  float mu = s * (1.f / 1024.f);
  float var = sq * (1.f / 1024.f) - mu * mu;
  float rsq = rsqrtf(var + 1e-5f);
  float4 w = ((const float4*)lnw)[tid];
  float4 bb = ((const float4*)lnb)[tid];
  bf16x4 o;
  o[0] = (__bf16)((x.x - mu) * rsq * w.x + bb.x);
  o[1] = (__bf16)((x.y - mu) * rsq * w.y + bb.y);
  o[2] = (__bf16)((x.z - mu) * rsq * w.z + bb.z);
  o[3] = (__bf16)((x.w - mu) * rsq * w.w + bb.w);
  ((bf16x4*)(lnbf + (size_t)r * H_))[tid] = o;
}

// ---------------------------------------------------------------------------
// Kernel 4: out = LN(attn) @ out_w.T  (M=2048,N=1024,K=1024), 64x64 tiles,
// BK=64 (16 K-iters, 4 MFMA/iter), register-prefetched.
// ---------------------------------------------------------------------------
#define APITCH 68  // bf16 pitch for BK=64: word-stride 34 % 32 == 2 -> free

__global__ __launch_bounds__(256) void gemm_kernel(const __bf16* __restrict__ A,
                                                   const __bf16* __restrict__ Bw,
                                                   float* __restrict__ out) {
  __shared__ __bf16 As[64 * APITCH];
  __shared__ __bf16 Bs[64 * APITCH];
  int tid = threadIdx.x;
  int n0 = (blockIdx.x & 15) * 64;
  int m0 = (blockIdx.x >> 4) * 64;
  int wave = tid >> 6, lane = tid & 63;
  int l31 = lane & 31, dh = lane >> 5;
  int mq = (wave >> 1) * 32, nq = (wave & 1) * 32;
  int srow = tid >> 2, skoff = (tid & 3) * 16;
  f32x16 acc;
#pragma unroll
  for (int i = 0; i < 16; i++) acc[i] = 0.f;

  union U8 { bf16x8 v; bf16x4 hh[2]; };
  U8 av0, av1, bv0, bv1, avn0, avn1, bvn0, bvn1;
  av0.v = *(const bf16x8*)(A + (size_t)(m0 + srow) * 1024 + skoff);
  av1.v = *(const bf16x8*)(A + (size_t)(m0 + srow) * 1024 + skoff + 8);
  bv0.v = *(const bf16x8*)(Bw + (size_t)(n0 + srow) * 1024 + skoff);
  bv1.v = *(const bf16x8*)(Bw + (size_t)(n0 + srow) * 1024 + skoff + 8);

#pragma unroll 1
  for (int kb = 0; kb < 1024; kb += 64) {
    *(bf16x4*)(As + srow * APITCH + skoff) = av0.hh[0];
    *(bf16x4*)(As + srow * APITCH + skoff + 4) = av0.hh[1];
    *(bf16x4*)(As + srow * APITCH + skoff + 8) = av1.hh[0];
    *(bf16x4*)(As + srow * APITCH + skoff + 12) = av1.hh[1];
    *(bf16x4*)(Bs + srow * APITCH + skoff) = bv0.hh[0];
    *(bf16x4*)(Bs + srow * APITCH + skoff + 4) = bv0.hh[1];
    *(bf16x4*)(Bs + srow * APITCH + skoff + 8) = bv1.hh[0];
    *(bf16x4*)(Bs + srow * APITCH + skoff + 12) = bv1.hh[1];
    __syncthreads();
    if (kb < 960) {
      const __bf16* ap = A + (size_t)(m0 + srow) * 1024 + kb + 64 + skoff;
      const __bf16* bp = Bw + (size_t)(n0 + srow) * 1024 + kb + 64 + skoff;
      avn0.v = *(const bf16x8*)ap;
      avn1.v = *(const bf16x8*)(ap + 8);
      bvn0.v = *(const bf16x8*)bp;
      bvn1.v = *(const bf16x8*)(bp + 8);
    }
#pragma unroll
    for (int kk = 0; kk < 64; kk += 16) {
      U8 af, bf;
      const __bf16* ap = As + (mq + l31) * APITCH + kk + dh * 8;
      const __bf16* bp = Bs + (nq + l31) * APITCH + kk + dh * 8;
      af.hh[0] = *(const bf16x4*)ap;
      af.hh[1] = *(const bf16x4*)(ap + 4);
      bf.hh[0] = *(const bf16x4*)bp;
      bf.hh[1] = *(const bf16x4*)(bp + 4);
      acc = __builtin_amdgcn_mfma_f32_32x32x16_bf16(af.v, bf.v, acc, 0, 0, 0);
    }
    __syncthreads();
    av0 = avn0; av1 = avn1; bv0 = bvn0; bv1 = bvn1;
  }
#pragma unroll
  for (int i = 0; i < 16; i++) {
    int r = (i & 3) + 4 * dh + 8 * (i >> 2);
    out[(size_t)(m0 + mq + r) * 1024 + n0 + nq + l31] = acc[i];
  }
}

// ---------------------------------------------------------------------------
extern "C" void kernel_launch(void* const* d_in, const int* in_sizes, int n_in,
                              void* d_out, int out_size, void* d_ws, size_t ws_size,
                              hipStream_t stream) {
  const float* q = (const float*)d_in[0];
  const float* k = (const float*)d_in[1];
  const float* v = (const float*)d_in[2];
  const float* bias = (const float*)d_in[3];
  const float* law = (const float*)d_in[4];
  const float* outw = (const float*)d_in[5];
  const float* lnw = (const float*)d_in[6];
  const float* lnb = (const float*)d_in[7];
  const int* outcell = (const int*)d_in[9];
  float* out = (float*)d_out;

  char* ws = (char*)d_ws;
  __bf16* Kx = (__bf16*)ws;                       // 6,291,456 B
  __bf16* Vt = (__bf16*)(ws + 6291456);           // 6,291,456 B
  float* attnws = (float*)(ws + 12582912);        // 8,388,608 B
  __bf16* lnbf = (__bf16*)(ws + 20971520);        // 4,194,304 B
  __bf16* wbf = (__bf16*)(ws + 25165824);         // 2,097,152 B

  hipLaunchKernelGGL(prep_kernel, dim3(2560), dim3(256), 0, stream,
                     k, v, outcell, Kx, Vt, outw, wbf);
  hipLaunchKernelGGL(attn_kernel, dim3(4 * 32 * 16), dim3(256), 0, stream,
                     q, Kx, Vt, bias, law, attnws);
  hipLaunchKernelGGL(ln_kernel, dim3(2048), dim3(256), 0, stream,
                     attnws, lnw, lnb, lnbf);
  hipLaunchKernelGGL(gemm_kernel, dim3(512), dim3(256), 0, stream,
                     lnbf, wbf, out);
}